// Round 3
// baseline (165.105 us; speedup 1.0000x reference)
//
#include <hip/hip_runtime.h>
#include <math.h>

#define IN_DIM 8192
#define H_DIM 4096

__device__ __forceinline__ float sigmoidf_(float x) {
    return 1.0f / (1.0f + __expf(-x));
}

__device__ __forceinline__ float wave_reduce_sum(float v) {
    #pragma unroll
    for (int off = 32; off > 0; off >>= 1)
        v += __shfl_xor(v, off, 64);
    return v;
}

__device__ __forceinline__ void st_agent(float* p, float v) {
    __hip_atomic_store(p, v, __ATOMIC_RELAXED, __HIP_MEMORY_SCOPE_AGENT);
}
__device__ __forceinline__ float ld_agent(const float* p) {
    return __hip_atomic_load(p, __ATOMIC_RELAXED, __HIP_MEMORY_SCOPE_AGENT);
}

// Kernel 1: z = relu(W1 @ x + b1)   [4096 rows, 8192 cols]
//           hhp = W_hh @ h0 + b_hh + b_ih   [16384 rows, 4096 cols]
// One wave per output row. 4 waves / block. Also zeroes k2's block counter.
__global__ __launch_bounds__(256) void k1_z_hh(
        const float* __restrict__ W1, const float* __restrict__ x,
        const float* __restrict__ b1,
        const float* __restrict__ W_hh, const float* __restrict__ h0,
        const float* __restrict__ b_hh, const float* __restrict__ b_ih,
        float* __restrict__ z, float* __restrict__ hhp,
        unsigned int* __restrict__ counter) {
    if (blockIdx.x == 0 && threadIdx.x == 0) {
        __hip_atomic_store(counter, 0u, __ATOMIC_RELAXED, __HIP_MEMORY_SCOPE_AGENT);
    }
    const int wave = blockIdx.x * 4 + (threadIdx.x >> 6);
    const int lane = threadIdx.x & 63;

    if (wave < H_DIM) {
        // z row: 8192 floats = 2048 float4; 32 iters of 64 lanes
        const float4* row = (const float4*)(W1 + (size_t)wave * IN_DIM);
        const float4* xv  = (const float4*)x;
        float acc = 0.0f;
        #pragma unroll
        for (int it = 0; it < 32; ++it) {
            const int idx = it * 64 + lane;
            float4 w = row[idx];
            float4 v = xv[idx];
            acc += w.x * v.x + w.y * v.y + w.z * v.z + w.w * v.w;
        }
        acc = wave_reduce_sum(acc);
        if (lane == 0) z[wave] = fmaxf(acc + b1[wave], 0.0f);
    } else {
        const int r = wave - H_DIM;  // 0 .. 16383
        const float4* row = (const float4*)(W_hh + (size_t)r * H_DIM);
        const float4* hv  = (const float4*)h0;
        float acc = 0.0f;
        #pragma unroll
        for (int it = 0; it < 16; ++it) {
            const int idx = it * 64 + lane;
            float4 w = row[idx];
            float4 v = hv[idx];
            acc += w.x * v.x + w.y * v.y + w.z * v.z + w.w * v.w;
        }
        acc = wave_reduce_sum(acc);
        if (lane == 0) hhp[r] = acc + b_hh[r] + b_ih[r];
    }
}

// Kernel 2: per hidden j (one wave each): 4 gate dots W_ih[j + g*4096] . z,
// add hhp, LSTM elementwise, write h_new / c_new. Last block to finish also
// computes the head: a = sigmoid(W3 . h + b3), lag blend, y1.
__global__ __launch_bounds__(256) void k2_ih_lstm_head(
        const float* __restrict__ W_ih, const float* __restrict__ z,
        const float* __restrict__ hhp, const float* __restrict__ c0,
        const float* __restrict__ W3, const float* __restrict__ b3,
        const float* __restrict__ u, const float* __restrict__ a_pre,
        const float* __restrict__ y_pre,
        float* __restrict__ d_out,     // y1[0], h[1..4096], c[4097..8192], a[8193]
        float* __restrict__ h_ws,      // agent-visible h copy for the head
        unsigned int* __restrict__ counter) {
    const int j = blockIdx.x * 4 + (threadIdx.x >> 6);  // 0..4095
    const int lane = threadIdx.x & 63;
    const int t = threadIdx.x;
    const float4* zv = (const float4*)z;

    float acc[4];
    #pragma unroll
    for (int g = 0; g < 4; ++g) {
        const float4* row = (const float4*)(W_ih + (size_t)(j + g * H_DIM) * H_DIM);
        float a = 0.0f;
        #pragma unroll
        for (int it = 0; it < 16; ++it) {
            const int idx = it * 64 + lane;
            float4 w = row[idx];
            float4 v = zv[idx];
            a += w.x * v.x + w.y * v.y + w.z * v.z + w.w * v.w;
        }
        acc[g] = a;
    }
    #pragma unroll
    for (int g = 0; g < 4; ++g) acc[g] = wave_reduce_sum(acc[g]);

    if (lane == 0) {
        const float gi = acc[0] + hhp[j];
        const float gf = acc[1] + hhp[j + H_DIM];
        const float gg = acc[2] + hhp[j + 2 * H_DIM];
        const float go = acc[3] + hhp[j + 3 * H_DIM];
        const float cn = sigmoidf_(gf) * c0[j] + sigmoidf_(gi) * tanhf(gg);
        const float hn = sigmoidf_(go) * tanhf(cn);
        d_out[1 + j] = hn;
        d_out[1 + H_DIM + j] = cn;
        st_agent(h_ws + j, hn);   // device-scope store -> coherence point
    }

    // ---- last-block head ----
    __shared__ int is_last;
    __shared__ float red[4];
    __syncthreads();  // drains vmcnt(0): agent stores above have completed
    if (t == 0) {
        unsigned int old = __hip_atomic_fetch_add(counter, 1u, __ATOMIC_ACQ_REL,
                                                  __HIP_MEMORY_SCOPE_AGENT);
        is_last = (old == (unsigned int)(gridDim.x - 1));
    }
    __syncthreads();
    if (!is_last) return;

    // all h_ws entries are at the coherence point; read with agent scope
    float acc2 = 0.0f;
    #pragma unroll
    for (int it = 0; it < 16; ++it) {
        const int idx = it * 256 + t;  // 0..4095
        acc2 += W3[idx] * ld_agent(h_ws + idx);
    }
    acc2 = wave_reduce_sum(acc2);
    if (lane == 0) red[t >> 6] = acc2;
    __syncthreads();
    if (t == 0) {
        const float dot = red[0] + red[1] + red[2] + red[3];
        const float a_new = sigmoidf_(dot + b3[0]);
        const float uu = u[0];
        const float a = uu * a_pre[0] + (1.0f - uu) * a_new;
        const float y1 = a * uu + (1.0f - a) * y_pre[0];
        d_out[0] = y1;
        d_out[1 + 2 * H_DIM] = a;  // index 8193
    }
}

extern "C" void kernel_launch(void* const* d_in, const int* in_sizes, int n_in,
                              void* d_out, int out_size, void* d_ws, size_t ws_size,
                              hipStream_t stream) {
    const float* x     = (const float*)d_in[0];
    const float* u     = (const float*)d_in[1];
    const float* h0    = (const float*)d_in[2];
    const float* c0    = (const float*)d_in[3];
    const float* y_pre = (const float*)d_in[4];
    const float* a_pre = (const float*)d_in[5];
    const float* W1    = (const float*)d_in[6];
    const float* b1    = (const float*)d_in[7];
    const float* W_ih  = (const float*)d_in[8];
    const float* b_ih  = (const float*)d_in[9];
    const float* W_hh  = (const float*)d_in[10];
    const float* b_hh  = (const float*)d_in[11];
    const float* W3    = (const float*)d_in[12];
    const float* b3    = (const float*)d_in[13];

    float* out = (float*)d_out;

    // Workspace (floats): z[4096] | hhp[16384] | h_ws[4096] | counter
    float* z   = (float*)d_ws;
    float* hhp = z + H_DIM;
    float* hws = hhp + 4 * H_DIM;
    unsigned int* counter = (unsigned int*)(hws + H_DIM);

    // k1: 4096 + 16384 = 20480 waves, 4 waves/block -> 5120 blocks
    k1_z_hh<<<5120, 256, 0, stream>>>(W1, x, b1, W_hh, h0, b_hh, b_ih,
                                      z, hhp, counter);

    // k2: 4096 waves, 4/block -> 1024 blocks; last block does the head
    k2_ih_lstm_head<<<1024, 256, 0, stream>>>(W_ih, z, hhp, c0, W3, b3,
                                              u, a_pre, y_pre, out, hws, counter);
}

// Round 4
// 120.087 us; speedup vs baseline: 1.3749x; 1.3749x over previous
//
#include <hip/hip_runtime.h>
#include <math.h>

#define IN_DIM 8192
#define H_DIM 4096

__device__ __forceinline__ float sigmoidf_(float x) {
    return 1.0f / (1.0f + __expf(-x));
}

__device__ __forceinline__ float wave_reduce_sum(float v) {
    #pragma unroll
    for (int off = 32; off > 0; off >>= 1)
        v += __shfl_xor(v, off, 64);
    return v;
}

// Kernel 1 (uniform 16-iter waves):
//   blocks 0..2047:    2 z-rows each; 2 waves per row (half-row each), LDS combine.
//                      z = relu(W1 @ x + b1)
//   blocks 2048..6143: 4 W_hh rows each (one per wave).
//                      hhp = W_hh @ h0 + b_hh + b_ih
__global__ __launch_bounds__(256) void k1_z_hh(
        const float* __restrict__ W1, const float* __restrict__ x,
        const float* __restrict__ b1,
        const float* __restrict__ W_hh, const float* __restrict__ h0,
        const float* __restrict__ b_hh, const float* __restrict__ b_ih,
        float* __restrict__ z, float* __restrict__ hhp) {
    const int w = threadIdx.x >> 6;
    const int lane = threadIdx.x & 63;
    const int b = blockIdx.x;
    __shared__ float part[4];

    if (b < 2048) {
        const int row = b * 2 + (w >> 1);       // 2 rows per block
        const int half = w & 1;                 // half-row per wave
        const float4* rp = (const float4*)(W1 + (size_t)row * IN_DIM);
        const float4* xv = (const float4*)x;
        float acc = 0.0f;
        #pragma unroll
        for (int it = 0; it < 16; ++it) {
            const int idx = half * 1024 + it * 64 + lane;
            float4 wv = rp[idx];
            float4 v  = xv[idx];
            acc += wv.x * v.x + wv.y * v.y + wv.z * v.z + wv.w * v.w;
        }
        acc = wave_reduce_sum(acc);
        if (lane == 0) part[w] = acc;
        __syncthreads();
        if (threadIdx.x < 2) {
            const int r = b * 2 + threadIdx.x;
            z[r] = fmaxf(part[threadIdx.x * 2] + part[threadIdx.x * 2 + 1] + b1[r], 0.0f);
        }
    } else {
        const int r = (b - 2048) * 4 + w;       // 0 .. 16383
        const float4* rp = (const float4*)(W_hh + (size_t)r * H_DIM);
        const float4* hv = (const float4*)h0;
        float acc = 0.0f;
        #pragma unroll
        for (int it = 0; it < 16; ++it) {
            const int idx = it * 64 + lane;
            float4 wv = rp[idx];
            float4 v  = hv[idx];
            acc += wv.x * v.x + wv.y * v.y + wv.z * v.z + wv.w * v.w;
        }
        acc = wave_reduce_sum(acc);
        if (lane == 0) hhp[r] = acc + b_hh[r] + b_ih[r];
    }
}

// Kernel 2: one block per hidden j. Wave g computes W_ih[j + g*4096] . z
// (16 iters), LDS combine, thread 0 does the LSTM elementwise and writes
// h_new / c_new (d_out) + aligned h copy (ws).
__global__ __launch_bounds__(256) void k2_ih_lstm(
        const float* __restrict__ W_ih, const float* __restrict__ z,
        const float* __restrict__ hhp, const float* __restrict__ c0,
        float* __restrict__ out_h,   // d_out + 1
        float* __restrict__ out_c,   // d_out + 1 + 4096
        float* __restrict__ h_ws) {
    const int j = blockIdx.x;                   // 0..4095
    const int g = threadIdx.x >> 6;
    const int lane = threadIdx.x & 63;
    __shared__ float part[4];

    const float4* rp = (const float4*)(W_ih + (size_t)(j + g * H_DIM) * H_DIM);
    const float4* zv = (const float4*)z;
    float acc = 0.0f;
    #pragma unroll
    for (int it = 0; it < 16; ++it) {
        const int idx = it * 64 + lane;
        float4 wv = rp[idx];
        float4 v  = zv[idx];
        acc += wv.x * v.x + wv.y * v.y + wv.z * v.z + wv.w * v.w;
    }
    acc = wave_reduce_sum(acc);
    if (lane == 0) part[g] = acc;
    __syncthreads();

    if (threadIdx.x == 0) {
        const float gi = part[0] + hhp[j];
        const float gf = part[1] + hhp[j + H_DIM];
        const float gg = part[2] + hhp[j + 2 * H_DIM];
        const float go = part[3] + hhp[j + 3 * H_DIM];
        const float cn = sigmoidf_(gf) * c0[j] + sigmoidf_(gi) * tanhf(gg);
        const float hn = sigmoidf_(go) * tanhf(cn);
        out_h[j] = hn;
        out_c[j] = cn;
        h_ws[j] = hn;
    }
}

// Kernel 3: a_new = sigmoid(W3 . h + b3); lag blend; write y1 and a.
// Single block, 256 threads.
__global__ __launch_bounds__(256) void k3_head(
        const float* __restrict__ W3, const float* __restrict__ b3,
        const float* __restrict__ h_ws,
        const float* __restrict__ u, const float* __restrict__ a_pre,
        const float* __restrict__ y_pre,
        float* __restrict__ d_out) {  // y1 at [0], a at [8193]
    __shared__ float red[4];
    const int t = threadIdx.x;
    const int lane = t & 63;
    const int wid = t >> 6;

    const float4* wv = (const float4*)W3;
    const float4* hv = (const float4*)h_ws;
    float acc = 0.0f;
    #pragma unroll
    for (int it = 0; it < 4; ++it) {
        const int idx = it * 256 + t;  // 1024 float4 total
        float4 w = wv[idx];
        float4 v = hv[idx];
        acc += w.x * v.x + w.y * v.y + w.z * v.z + w.w * v.w;
    }
    acc = wave_reduce_sum(acc);
    if (lane == 0) red[wid] = acc;
    __syncthreads();
    if (t == 0) {
        const float dot = red[0] + red[1] + red[2] + red[3];
        const float a_new = sigmoidf_(dot + b3[0]);
        const float uu = u[0];
        const float ap = a_pre[0];
        const float yp = y_pre[0];
        const float a = uu * ap + (1.0f - uu) * a_new;
        const float y1 = a * uu + (1.0f - a) * yp;
        d_out[0] = y1;
        d_out[1 + 2 * H_DIM] = a;  // index 8193
    }
}

extern "C" void kernel_launch(void* const* d_in, const int* in_sizes, int n_in,
                              void* d_out, int out_size, void* d_ws, size_t ws_size,
                              hipStream_t stream) {
    const float* x     = (const float*)d_in[0];
    const float* u     = (const float*)d_in[1];
    const float* h0    = (const float*)d_in[2];
    const float* c0    = (const float*)d_in[3];
    const float* y_pre = (const float*)d_in[4];
    const float* a_pre = (const float*)d_in[5];
    const float* W1    = (const float*)d_in[6];
    const float* b1    = (const float*)d_in[7];
    const float* W_ih  = (const float*)d_in[8];
    const float* b_ih  = (const float*)d_in[9];
    const float* W_hh  = (const float*)d_in[10];
    const float* b_hh  = (const float*)d_in[11];
    const float* W3    = (const float*)d_in[12];
    const float* b3    = (const float*)d_in[13];

    float* out = (float*)d_out;

    // Workspace layout (floats): z[4096] | hhp[16384] | h_new[4096]
    float* z   = (float*)d_ws;
    float* hhp = z + H_DIM;
    float* hws = hhp + 4 * H_DIM;

    // k1: 2048 z-blocks + 4096 hh-blocks = 6144 uniform blocks
    k1_z_hh<<<6144, 256, 0, stream>>>(W1, x, b1, W_hh, h0, b_hh, b_ih, z, hhp);

    // k2: one block per hidden j
    k2_ih_lstm<<<4096, 256, 0, stream>>>(W_ih, z, hhp, c0,
                                         out + 1, out + 1 + H_DIM, hws);

    // k3: single block
    k3_head<<<1, 256, 0, stream>>>(W3, b3, hws, u, a_pre, y_pre, out);
}